// Round 9
// baseline (317.550 us; speedup 1.0000x reference)
//
#include <hip/hip_runtime.h>

// ImpedanceAwareGCN on MI355X.
// segment_sum(out[row] + imp[row]*imp_mod[col], col)
//   = scatter_add(out) + S[v]*imp_mod[v],  S[v] = sum_{e: col=v} imp[row[e]].
// R9: gather split into two half-row (64B line) passes steered to disjoint
// XCD sets via blockIdx%8 -> per-XCD gather footprint 12.8MB -> 6.4MB,
// raising per-XCD L2 hit rate (R8 FETCH_SIZE showed 8x XCD duplication).

#define BINW    128          // nodes per bin (bin = col >> 7)
#define CHUNK   4096         // edges per binning block
#define BINCAP  3072         // Phase-B LDS edge cap (mean 2046, +22 sigma)

typedef __attribute__((ext_vector_type(8))) short bf16x8;
typedef __attribute__((ext_vector_type(4))) float f32x4;

__device__ inline unsigned short f2bf(float f) {   // RNE fp32->bf16
    unsigned u = __float_as_uint(f);
    unsigned r = u + 0x7fffu + ((u >> 16) & 1u);
    return (unsigned short)(r >> 16);
}
__device__ inline float bflo(unsigned u) { return __uint_as_float(u << 16); }
__device__ inline float bfhi(unsigned u) { return __uint_as_float(u & 0xffff0000u); }

// ---------------- Pass A1: per-bin histogram ----------------
__global__ __launch_bounds__(256) void bin_count(const int* __restrict__ col,
        int* __restrict__ binCnt, int E, int nbin) {
    __shared__ int hist[1024];
    int e0 = blockIdx.x * CHUNK;
    int cnt = E - e0; if (cnt > CHUNK) cnt = CHUNK;
    if (cnt <= 0) return;
    int tid = threadIdx.x;
    for (int b = tid; b < nbin; b += 256) hist[b] = 0;
    __syncthreads();
    for (int i = tid; i < cnt; i += 256) atomicAdd(&hist[col[e0 + i] >> 7], 1);
    __syncthreads();
    for (int b = tid; b < nbin; b += 256)
        if (hist[b]) atomicAdd(&binCnt[b], hist[b]);
}

// ---------------- Prefix: binBase = exclusive scan, zero cursors ----------------
__global__ __launch_bounds__(1024) void bin_prefix(const int* __restrict__ binCnt,
        int* __restrict__ binBase, int* __restrict__ cursor,
        int* __restrict__ node_ptr, int nbin, int n, int E) {
    __shared__ int sa[1024];
    int tid = threadIdx.x;
    sa[tid] = (tid < nbin) ? binCnt[tid] : 0;
    __syncthreads();
    for (int d = 1; d < 1024; d <<= 1) {
        int v = sa[tid] + ((tid >= d) ? sa[tid - d] : 0);
        __syncthreads();
        sa[tid] = v;
        __syncthreads();
    }
    if (tid < nbin) { binBase[tid] = sa[tid] - binCnt[tid]; cursor[tid] = 0; }
    if (tid == 0) node_ptr[n] = E;
}

// ---------------- Pass A2: scatter packed edges into correct bin segments ----------------
__global__ __launch_bounds__(256) void bin_scatter(const int* __restrict__ row,
        const int* __restrict__ col, const int* __restrict__ binBase,
        int* __restrict__ cursor, int* __restrict__ binBuf, int E, int nbin) {
    __shared__ int      wpackl[CHUNK];     // (row<<7) | (col&127)
    __shared__ unsigned short wbin[CHUNK];
    __shared__ int      hist[1024];
    __shared__ int      basel[1024];

    int e0 = blockIdx.x * CHUNK;
    int cnt = E - e0; if (cnt > CHUNK) cnt = CHUNK;
    if (cnt <= 0) return;
    int tid = threadIdx.x;

    for (int b = tid; b < nbin; b += 256) hist[b] = 0;
    for (int i = tid; i < cnt; i += 256) {
        int r = row[e0 + i], v = col[e0 + i];
        wpackl[i] = (r << 7) | (v & (BINW - 1));
        wbin[i]  = (unsigned short)(v >> 7);
    }
    __syncthreads();
    for (int i = tid; i < cnt; i += 256) atomicAdd(&hist[wbin[i]], 1);
    __syncthreads();
    for (int b = tid; b < nbin; b += 256) {
        int h = hist[b];
        basel[b] = h ? (binBase[b] + atomicAdd(&cursor[b], h)) : 0;
        hist[b] = 0;
    }
    __syncthreads();
    for (int i = tid; i < cnt; i += 256) {
        int b = wbin[i];
        int off = atomicAdd(&hist[b], 1);
        binBuf[basel[b] + off] = wpackl[i];
    }
}

// ---------------- Phase B: counting-sort each bin in LDS -> CSR rows, node_ptr, S ----------------
__global__ __launch_bounds__(256) void bin_phaseB(const int* __restrict__ binCnt,
        const int* __restrict__ binBase, const int* __restrict__ binBuf,
        const float* __restrict__ imp, int* __restrict__ rows,
        int* __restrict__ node_ptr, float* __restrict__ S, int n) {
    __shared__ int ein[BINCAP];
    __shared__ int sorted[BINCAP];
    __shared__ int dhist[BINW];
    __shared__ int dpre[BINW];
    __shared__ int doff[BINW];

    int b = blockIdx.x;
    int base = binBase[b];
    int cnt = binCnt[b]; if (cnt > BINCAP) cnt = BINCAP;
    int tid = threadIdx.x;
    int v0 = b << 7;

    if (tid < BINW) { dhist[tid] = 0; doff[tid] = 0; }
    for (int i = tid; i < cnt; i += 256) ein[i] = binBuf[base + i];
    __syncthreads();
    for (int i = tid; i < cnt; i += 256) atomicAdd(&dhist[ein[i] & (BINW - 1)], 1);
    __syncthreads();
    if (tid < BINW) dpre[tid] = dhist[tid];
    __syncthreads();
    for (int d = 1; d < BINW; d <<= 1) {
        int v = 0;
        if (tid < BINW) v = dpre[tid] + ((tid >= d) ? dpre[tid - d] : 0);
        __syncthreads();
        if (tid < BINW) dpre[tid] = v;
        __syncthreads();
    }
    if (tid < BINW) {
        int v = v0 + tid;
        if (v < n) node_ptr[v] = base + dpre[tid] - dhist[tid];
    }
    __syncthreads();
    for (int i = tid; i < cnt; i += 256) {
        int w = ein[i];
        int j = w & (BINW - 1);
        int off = atomicAdd(&doff[j], 1);
        sorted[dpre[j] - dhist[j] + off] = w >> 7;
    }
    __syncthreads();
    for (int i = tid; i < cnt; i += 256) rows[base + i] = sorted[i];
    if (tid < BINW) {
        int v = v0 + tid;
        if (v < n) {
            int a = dpre[tid] - dhist[tid], e = dpre[tid];
            float s0 = 0.f, s1 = 0.f;
            int i = a;
            for (; i + 2 <= e; i += 2) { s0 += imp[sorted[i]]; s1 += imp[sorted[i + 1]]; }
            if (i < e) s0 += imp[sorted[i]];
            S[v] = s0 + s1;
        }
    }
}

// ---------------- x -> bf16 convert (layer-1 A operand) ----------------
__global__ __launch_bounds__(256) void xconv(const float* __restrict__ x,
        unsigned short* __restrict__ xb, long total8) {
    long i = (long)blockIdx.x * 256 + threadIdx.x;
    if (i >= total8) return;
    const float4* xp = (const float4*)(x + i * 8);
    float4 a = xp[0], b = xp[1];
    uint4 w = make_uint4(
        (unsigned)f2bf(a.x) | ((unsigned)f2bf(a.y) << 16),
        (unsigned)f2bf(a.z) | ((unsigned)f2bf(a.w) << 16),
        (unsigned)f2bf(b.x) | ((unsigned)f2bf(b.y) << 16),
        (unsigned)f2bf(b.z) | ((unsigned)f2bf(b.w) << 16));
    *(uint4*)(xb + i * 8) = w;
}

// ---------------- weight pack: fragment layout [m][kc][ct][lane][8], bf16 ----------------
__global__ __launch_bounds__(256) void wpack_all(
        const float* __restrict__ W1, const float* __restrict__ Wi1,
        const float* __restrict__ W2, const float* __restrict__ Wi2,
        const float* __restrict__ W3, const float* __restrict__ Wi3,
        unsigned short* __restrict__ wf1, unsigned short* __restrict__ wf2,
        unsigned short* __restrict__ wf3) {
    int blk = blockIdx.x;
    const float *W, *Wi; unsigned short* dst; int KC;
    if (blk == 0)      { W = W1; Wi = Wi1; dst = wf1; KC = 1; }
    else if (blk == 1) { W = W2; Wi = Wi2; dst = wf2; KC = 2; }
    else               { W = W3; Wi = Wi3; dst = wf3; KC = 2; }
    int SLOTS = 2 * KC * 4 * 64;
    for (int s = threadIdx.x; s < SLOTS; s += 256) {
        int l  = s & 63;
        int ct = (s >> 6) & 3;
        int kc = (s >> 8) % KC;
        int m  = s / (256 * KC);
        int k   = kc * 32 + ((l >> 4) << 3);
        int c   = ct * 16 + (l & 15);
        const float* src = m ? Wi : W;
        unsigned short t[8];
#pragma unroll
        for (int e = 0; e < 8; ++e) t[e] = f2bf(src[(k + e) * 64 + c]);
        *(uint4*)(dst + (size_t)s * 8) = make_uint4(
            (unsigned)t[0] | ((unsigned)t[1] << 16),
            (unsigned)t[2] | ((unsigned)t[3] << 16),
            (unsigned)t[4] | ((unsigned)t[5] << 16),
            (unsigned)t[6] | ((unsigned)t[7] << 16));
    }
}

// ---------------- MFMA dual GEMM: outb = bf16(in@W+b), nxt = S*(in@Wi) ----------------
template<int K>
__global__ __launch_bounds__(256) void gemm_mfma(
        const unsigned short* __restrict__ hb, const unsigned short* __restrict__ wf,
        const float* __restrict__ bias, const float* __restrict__ S,
        unsigned short* __restrict__ outb, float* __restrict__ nxt, int n) {
    constexpr int KC = K / 32;
    int lane = threadIdx.x & 63;
    int node0 = blockIdx.x * 64 + (threadIdx.x >> 6) * 16;
    if (node0 >= n) return;

    int arow = node0 + (lane & 15);
    if (arow >= n) arow = n - 1;
    const unsigned short* ap = hb + (size_t)arow * K + ((lane >> 4) << 3);

    f32x4 z = {0.f, 0.f, 0.f, 0.f};
    f32x4 accW[4] = {z, z, z, z};
    f32x4 accI[4] = {z, z, z, z};

#pragma unroll
    for (int kc = 0; kc < KC; ++kc) {
        bf16x8 a = *(const bf16x8*)(ap + kc * 32);
#pragma unroll
        for (int ct = 0; ct < 4; ++ct) {
            bf16x8 bw = *(const bf16x8*)(wf + ((((size_t)0 * KC + kc) * 4 + ct) * 64 + lane) * 8);
            bf16x8 bi = *(const bf16x8*)(wf + ((((size_t)1 * KC + kc) * 4 + ct) * 64 + lane) * 8);
            accW[ct] = __builtin_amdgcn_mfma_f32_16x16x32_bf16(a, bw, accW[ct], 0, 0, 0);
            accI[ct] = __builtin_amdgcn_mfma_f32_16x16x32_bf16(a, bi, accI[ct], 0, 0, 0);
        }
    }

    int colb = lane & 15;
    int rbase = node0 + ((lane >> 4) << 2);
    float sv[4];
#pragma unroll
    for (int j = 0; j < 4; ++j) {
        int r = rbase + j;
        sv[j] = (r < n) ? S[r] : 0.f;
    }
#pragma unroll
    for (int ct = 0; ct < 4; ++ct) {
        int c = ct * 16 + colb;
        float bb = bias[c];
#pragma unroll
        for (int j = 0; j < 4; ++j) {
            int r = rbase + j;
            if (r < n) {
                outb[(size_t)r * 64 + c] = f2bf(accW[ct][j] + bb);
                nxt [(size_t)r * 64 + c] = sv[j] * accI[ct][j];
            }
        }
    }
}

// ---------------- Gather, channel-split + XCD-steered ----------------
// Each block: 64 nodes x one half-row (32ch = one 64B line). blockIdx%8 -> XCD
// (round-robin); XCDs 0-3 take half 0, XCDs 4-7 take half 1, so each XCD's L2
// only holds a 6.4MB half-table. MODE 0: bf16+leaky-relu to hb. MODE 1: fp32 nxt.
template<int MODE>
__global__ __launch_bounds__(256) void gather_half(const int* __restrict__ node_ptr,
        const int* __restrict__ rows, const unsigned short* __restrict__ outb,
        float* __restrict__ nxt, unsigned short* __restrict__ hb, int n, int nvb) {
    int xcd  = blockIdx.x & 7;
    int half = xcd >> 2;
    int vb   = (blockIdx.x >> 3) * 4 + (xcd & 3);
    if (vb >= nvb) return;
    int t = threadIdx.x;
    int v = vb * 64 + (t >> 2);
    if (v >= n) return;
    int ch0 = half * 32 + (t & 3) * 8;     // 8 channels per thread
    int p0 = node_ptr[v], p1 = node_ptr[v + 1];

    float* np = nxt + (size_t)v * 64 + ch0;
    float4 n0 = *(float4*)np;
    float4 n1 = *(float4*)(np + 4);
    float acc[8] = {n0.x, n0.y, n0.z, n0.w, n1.x, n1.y, n1.z, n1.w};

    int i = p0;
    for (; i + 4 <= p1; i += 4) {
        int4 rr = *(const int4*)(rows + i);    // broadcast within 4-thread group
        uint4 a0 = *(const uint4*)(outb + (size_t)rr.x * 64 + ch0);
        uint4 a1 = *(const uint4*)(outb + (size_t)rr.y * 64 + ch0);
        uint4 a2 = *(const uint4*)(outb + (size_t)rr.z * 64 + ch0);
        uint4 a3 = *(const uint4*)(outb + (size_t)rr.w * 64 + ch0);
        acc[0] += bflo(a0.x) + bflo(a1.x) + bflo(a2.x) + bflo(a3.x);
        acc[1] += bfhi(a0.x) + bfhi(a1.x) + bfhi(a2.x) + bfhi(a3.x);
        acc[2] += bflo(a0.y) + bflo(a1.y) + bflo(a2.y) + bflo(a3.y);
        acc[3] += bfhi(a0.y) + bfhi(a1.y) + bfhi(a2.y) + bfhi(a3.y);
        acc[4] += bflo(a0.z) + bflo(a1.z) + bflo(a2.z) + bflo(a3.z);
        acc[5] += bfhi(a0.z) + bfhi(a1.z) + bfhi(a2.z) + bfhi(a3.z);
        acc[6] += bflo(a0.w) + bflo(a1.w) + bflo(a2.w) + bflo(a3.w);
        acc[7] += bfhi(a0.w) + bfhi(a1.w) + bfhi(a2.w) + bfhi(a3.w);
    }
    for (; i < p1; ++i) {
        int r = rows[i];
        uint4 a = *(const uint4*)(outb + (size_t)r * 64 + ch0);
        acc[0] += bflo(a.x); acc[1] += bfhi(a.x);
        acc[2] += bflo(a.y); acc[3] += bfhi(a.y);
        acc[4] += bflo(a.z); acc[5] += bfhi(a.z);
        acc[6] += bflo(a.w); acc[7] += bfhi(a.w);
    }
    if (MODE == 0) {
        unsigned w[4];
#pragma unroll
        for (int q = 0; q < 4; ++q) {
            float v0 = acc[2 * q], v1 = acc[2 * q + 1];
            v0 = (v0 >= 0.f) ? v0 : 0.2f * v0;
            v1 = (v1 >= 0.f) ? v1 : 0.2f * v1;
            w[q] = (unsigned)f2bf(v0) | ((unsigned)f2bf(v1) << 16);
        }
        *(uint4*)(hb + (size_t)v * 64 + ch0) = make_uint4(w[0], w[1], w[2], w[3]);
    } else {
        *(float4*)np       = make_float4(acc[0], acc[1], acc[2], acc[3]);
        *(float4*)(np + 4) = make_float4(acc[4], acc[5], acc[6], acc[7]);
    }
}

// ---------------- FC head ----------------
__global__ __launch_bounds__(256) void fc_kernel(const float* __restrict__ h,
        const float* __restrict__ Wfc, const float* __restrict__ bfc,
        float* __restrict__ o, int n) {
    int node = blockIdx.x * 4 + (threadIdx.x >> 6);
    int lane = threadIdx.x & 63;
    float v = 0.f;
    if (node < n) v = h[(size_t)node * 64 + lane] * Wfc[lane];
#pragma unroll
    for (int off = 32; off; off >>= 1) v += __shfl_down(v, off, 64);
    if (node < n && lane == 0) o[node] = v + bfc[0];
}

extern "C" void kernel_launch(void* const* d_in, const int* in_sizes, int n_in,
                              void* d_out, int out_size, void* d_ws, size_t ws_size,
                              hipStream_t stream) {
    const float* x   = (const float*)d_in[0];
    const int*   ei  = (const int*)d_in[1];
    const float* imp = (const float*)d_in[2];
    const float* W1  = (const float*)d_in[3];
    const float* b1  = (const float*)d_in[4];
    const float* Wi1 = (const float*)d_in[5];
    const float* W2  = (const float*)d_in[6];
    const float* b2  = (const float*)d_in[7];
    const float* Wi2 = (const float*)d_in[8];
    const float* W3  = (const float*)d_in[9];
    const float* b3  = (const float*)d_in[10];
    const float* Wi3 = (const float*)d_in[11];
    const float* Wfc = (const float*)d_in[12];
    const float* bfc = (const float*)d_in[13];

    int n = in_sizes[0] / 32;      // 100000
    int E = in_sizes[1] / 2;       // 1600000
    const int* row = ei;
    const int* col = ei + E;
    int nbin = (n + BINW - 1) / BINW;   // 782

    // ---- workspace: bump allocator, 64B-aligned regions ----
    size_t off = 0;
    auto alloc = [&](size_t words) {
        size_t cur = off;
        off += (words + 15) & ~(size_t)15;
        return cur;
    };
    int* wsw = (int*)d_ws;
    float*          S        = (float*)(wsw + alloc(n));
    int*            node_ptr = wsw + alloc((size_t)n + 1);
    int*            binCnt   = wsw + alloc(1024);
    int*            binBase  = wsw + alloc(1024);
    int*            cursor   = wsw + alloc(1024);
    int*            binBuf   = wsw + alloc(E);
    int*            rowsA    = wsw + alloc(E);
    float*          nxt      = (float*)(wsw + alloc((size_t)n * 64));
    unsigned short* outb     = (unsigned short*)(wsw + alloc((size_t)n * 32));
    unsigned short* hb       = (unsigned short*)(wsw + alloc((size_t)n * 32));
    unsigned short* xb       = (unsigned short*)(wsw + alloc((size_t)n * 16));
    unsigned short* wf1      = (unsigned short*)(wsw + alloc(2048));
    unsigned short* wf2      = (unsigned short*)(wsw + alloc(4096));
    unsigned short* wf3      = (unsigned short*)(wsw + alloc(4096));

    int gA = (E + CHUNK - 1) / CHUNK;

    hipMemsetAsync(binCnt, 0, 1024 * sizeof(int), stream);
    bin_count  <<<gA, 256, 0, stream>>>(col, binCnt, E, nbin);
    bin_prefix <<<1, 1024, 0, stream>>>(binCnt, binBase, cursor, node_ptr, nbin, n, E);
    bin_scatter<<<gA, 256, 0, stream>>>(row, col, binBase, cursor, binBuf, E, nbin);
    bin_phaseB <<<nbin, 256, 0, stream>>>(binCnt, binBase, binBuf, imp, rowsA, node_ptr, S, n);

    long total8 = (long)n * 32 / 8;
    xconv<<<(int)((total8 + 255) / 256), 256, 0, stream>>>(x, xb, total8);
    wpack_all<<<3, 256, 0, stream>>>(W1, Wi1, W2, Wi2, W3, Wi3, wf1, wf2, wf3);

    int gm  = (n + 63) / 64;            // mfma gemm blocks
    int nvb = (n + 63) / 64;            // gather node-blocks (64 nodes each)
    int ggh = ((nvb + 3) / 4) * 8;      // gather grid: slots x 8 XCD-steered blocks
    int gn4 = (n + 3) / 4;              // fc blocks

    // Layer 1 (K=32, input xb)
    gemm_mfma<32><<<gm, 256, 0, stream>>>(xb, wf1, b1, S, outb, nxt, n);
    gather_half<0><<<ggh, 256, 0, stream>>>(node_ptr, rowsA, outb, nxt, hb, n, nvb);

    // Layer 2 (K=64, input hb = relu'd bf16)
    gemm_mfma<64><<<gm, 256, 0, stream>>>(hb, wf2, b2, S, outb, nxt, n);
    gather_half<0><<<ggh, 256, 0, stream>>>(node_ptr, rowsA, outb, nxt, hb, n, nvb);

    // Layer 3 (K=64)
    gemm_mfma<64><<<gm, 256, 0, stream>>>(hb, wf3, b3, S, outb, nxt, n);
    gather_half<1><<<ggh, 256, 0, stream>>>(node_ptr, rowsA, outb, nxt, hb, n, nvb);

    // FC head
    fc_kernel<<<gn4, 256, 0, stream>>>(nxt, Wfc, bfc, (float*)d_out, n);
}

// Round 10
// 274.435 us; speedup vs baseline: 1.1571x; 1.1571x over previous
//
#include <hip/hip_runtime.h>

// ImpedanceAwareGCN on MI355X.
// segment_sum(out[row] + imp[row]*imp_mod[col], col)
//   = scatter_add(out) + S[v]*imp_mod[v],  S[v] = sum_{e: col=v} imp[row[e]].
// R10: revert R9's half-split gather (regressed: FETCH up, steering assumption
// falsified). Instead remove streaming traffic: imp_mod term stored bf16 (imb),
// gather+GEMM fused into one kernel (gather -> relu -> LDS -> MFMA), FC fused
// into the final gather. Eliminates hb + fp32 nxt roundtrips (~75 MB/layer).

#define BINW    128          // nodes per bin (bin = col >> 7)
#define CHUNK   4096         // edges per binning block
#define BINCAP  3072         // Phase-B LDS edge cap (mean 2046, +22 sigma)
#define LDSW    72           // LDS row stride in ushorts (64 + 8 pad)

typedef __attribute__((ext_vector_type(8))) short bf16x8;
typedef __attribute__((ext_vector_type(4))) float f32x4;

__device__ inline unsigned short f2bf(float f) {   // RNE fp32->bf16
    unsigned u = __float_as_uint(f);
    unsigned r = u + 0x7fffu + ((u >> 16) & 1u);
    return (unsigned short)(r >> 16);
}
__device__ inline float bflo(unsigned u) { return __uint_as_float(u << 16); }
__device__ inline float bfhi(unsigned u) { return __uint_as_float(u & 0xffff0000u); }

// ---------------- Pass A1: per-bin histogram ----------------
__global__ __launch_bounds__(256) void bin_count(const int* __restrict__ col,
        int* __restrict__ binCnt, int E, int nbin) {
    __shared__ int hist[1024];
    int e0 = blockIdx.x * CHUNK;
    int cnt = E - e0; if (cnt > CHUNK) cnt = CHUNK;
    if (cnt <= 0) return;
    int tid = threadIdx.x;
    for (int b = tid; b < nbin; b += 256) hist[b] = 0;
    __syncthreads();
    for (int i = tid; i < cnt; i += 256) atomicAdd(&hist[col[e0 + i] >> 7], 1);
    __syncthreads();
    for (int b = tid; b < nbin; b += 256)
        if (hist[b]) atomicAdd(&binCnt[b], hist[b]);
}

// ---------------- Prefix: binBase = exclusive scan, zero cursors ----------------
__global__ __launch_bounds__(1024) void bin_prefix(const int* __restrict__ binCnt,
        int* __restrict__ binBase, int* __restrict__ cursor,
        int* __restrict__ node_ptr, int nbin, int n, int E) {
    __shared__ int sa[1024];
    int tid = threadIdx.x;
    sa[tid] = (tid < nbin) ? binCnt[tid] : 0;
    __syncthreads();
    for (int d = 1; d < 1024; d <<= 1) {
        int v = sa[tid] + ((tid >= d) ? sa[tid - d] : 0);
        __syncthreads();
        sa[tid] = v;
        __syncthreads();
    }
    if (tid < nbin) { binBase[tid] = sa[tid] - binCnt[tid]; cursor[tid] = 0; }
    if (tid == 0) node_ptr[n] = E;
}

// ---------------- Pass A2: scatter packed edges into correct bin segments ----------------
__global__ __launch_bounds__(256) void bin_scatter(const int* __restrict__ row,
        const int* __restrict__ col, const int* __restrict__ binBase,
        int* __restrict__ cursor, int* __restrict__ binBuf, int E, int nbin) {
    __shared__ int      wpackl[CHUNK];     // (row<<7) | (col&127)
    __shared__ unsigned short wbin[CHUNK];
    __shared__ int      hist[1024];
    __shared__ int      basel[1024];

    int e0 = blockIdx.x * CHUNK;
    int cnt = E - e0; if (cnt > CHUNK) cnt = CHUNK;
    if (cnt <= 0) return;
    int tid = threadIdx.x;

    for (int b = tid; b < nbin; b += 256) hist[b] = 0;
    for (int i = tid; i < cnt; i += 256) {
        int r = row[e0 + i], v = col[e0 + i];
        wpackl[i] = (r << 7) | (v & (BINW - 1));
        wbin[i]  = (unsigned short)(v >> 7);
    }
    __syncthreads();
    for (int i = tid; i < cnt; i += 256) atomicAdd(&hist[wbin[i]], 1);
    __syncthreads();
    for (int b = tid; b < nbin; b += 256) {
        int h = hist[b];
        basel[b] = h ? (binBase[b] + atomicAdd(&cursor[b], h)) : 0;
        hist[b] = 0;
    }
    __syncthreads();
    for (int i = tid; i < cnt; i += 256) {
        int b = wbin[i];
        int off = atomicAdd(&hist[b], 1);
        binBuf[basel[b] + off] = wpackl[i];
    }
}

// ---------------- Phase B: counting-sort each bin in LDS -> CSR rows, node_ptr, S ----------------
__global__ __launch_bounds__(256) void bin_phaseB(const int* __restrict__ binCnt,
        const int* __restrict__ binBase, const int* __restrict__ binBuf,
        const float* __restrict__ imp, int* __restrict__ rows,
        int* __restrict__ node_ptr, float* __restrict__ S, int n) {
    __shared__ int ein[BINCAP];
    __shared__ int sorted[BINCAP];
    __shared__ int dhist[BINW];
    __shared__ int dpre[BINW];
    __shared__ int doff[BINW];

    int b = blockIdx.x;
    int base = binBase[b];
    int cnt = binCnt[b]; if (cnt > BINCAP) cnt = BINCAP;
    int tid = threadIdx.x;
    int v0 = b << 7;

    if (tid < BINW) { dhist[tid] = 0; doff[tid] = 0; }
    for (int i = tid; i < cnt; i += 256) ein[i] = binBuf[base + i];
    __syncthreads();
    for (int i = tid; i < cnt; i += 256) atomicAdd(&dhist[ein[i] & (BINW - 1)], 1);
    __syncthreads();
    if (tid < BINW) dpre[tid] = dhist[tid];
    __syncthreads();
    for (int d = 1; d < BINW; d <<= 1) {
        int v = 0;
        if (tid < BINW) v = dpre[tid] + ((tid >= d) ? dpre[tid - d] : 0);
        __syncthreads();
        if (tid < BINW) dpre[tid] = v;
        __syncthreads();
    }
    if (tid < BINW) {
        int v = v0 + tid;
        if (v < n) node_ptr[v] = base + dpre[tid] - dhist[tid];
    }
    __syncthreads();
    for (int i = tid; i < cnt; i += 256) {
        int w = ein[i];
        int j = w & (BINW - 1);
        int off = atomicAdd(&doff[j], 1);
        sorted[dpre[j] - dhist[j] + off] = w >> 7;
    }
    __syncthreads();
    for (int i = tid; i < cnt; i += 256) rows[base + i] = sorted[i];
    if (tid < BINW) {
        int v = v0 + tid;
        if (v < n) {
            int a = dpre[tid] - dhist[tid], e = dpre[tid];
            float s0 = 0.f, s1 = 0.f;
            int i = a;
            for (; i + 2 <= e; i += 2) { s0 += imp[sorted[i]]; s1 += imp[sorted[i + 1]]; }
            if (i < e) s0 += imp[sorted[i]];
            S[v] = s0 + s1;
        }
    }
}

// ---------------- x -> bf16 convert (layer-1 A operand) ----------------
__global__ __launch_bounds__(256) void xconv(const float* __restrict__ x,
        unsigned short* __restrict__ xb, long total8) {
    long i = (long)blockIdx.x * 256 + threadIdx.x;
    if (i >= total8) return;
    const float4* xp = (const float4*)(x + i * 8);
    float4 a = xp[0], b = xp[1];
    uint4 w = make_uint4(
        (unsigned)f2bf(a.x) | ((unsigned)f2bf(a.y) << 16),
        (unsigned)f2bf(a.z) | ((unsigned)f2bf(a.w) << 16),
        (unsigned)f2bf(b.x) | ((unsigned)f2bf(b.y) << 16),
        (unsigned)f2bf(b.z) | ((unsigned)f2bf(b.w) << 16));
    *(uint4*)(xb + i * 8) = w;
}

// ---------------- weight pack: fragment layout [m][kc][ct][lane][8], bf16 ----------------
__global__ __launch_bounds__(256) void wpack_all(
        const float* __restrict__ W1, const float* __restrict__ Wi1,
        const float* __restrict__ W2, const float* __restrict__ Wi2,
        const float* __restrict__ W3, const float* __restrict__ Wi3,
        unsigned short* __restrict__ wf1, unsigned short* __restrict__ wf2,
        unsigned short* __restrict__ wf3) {
    int blk = blockIdx.x;
    const float *W, *Wi; unsigned short* dst; int KC;
    if (blk == 0)      { W = W1; Wi = Wi1; dst = wf1; KC = 1; }
    else if (blk == 1) { W = W2; Wi = Wi2; dst = wf2; KC = 2; }
    else               { W = W3; Wi = Wi3; dst = wf3; KC = 2; }
    int SLOTS = 2 * KC * 4 * 64;
    for (int s = threadIdx.x; s < SLOTS; s += 256) {
        int l  = s & 63;
        int ct = (s >> 6) & 3;
        int kc = (s >> 8) % KC;
        int m  = s / (256 * KC);
        int k   = kc * 32 + ((l >> 4) << 3);
        int c   = ct * 16 + (l & 15);
        const float* src = m ? Wi : W;
        unsigned short t[8];
#pragma unroll
        for (int e = 0; e < 8; ++e) t[e] = f2bf(src[(k + e) * 64 + c]);
        *(uint4*)(dst + (size_t)s * 8) = make_uint4(
            (unsigned)t[0] | ((unsigned)t[1] << 16),
            (unsigned)t[2] | ((unsigned)t[3] << 16),
            (unsigned)t[4] | ((unsigned)t[5] << 16),
            (unsigned)t[6] | ((unsigned)t[7] << 16));
    }
}

// ---------------- Layer-1 MFMA dual GEMM: outb = bf16(x@W1+b1), imb = bf16(S*(x@Wi1)) ----------------
template<int K>
__global__ __launch_bounds__(256) void gemm_mfma(
        const unsigned short* __restrict__ hb, const unsigned short* __restrict__ wf,
        const float* __restrict__ bias, const float* __restrict__ S,
        unsigned short* __restrict__ outb, unsigned short* __restrict__ imb, int n) {
    constexpr int KC = K / 32;
    int lane = threadIdx.x & 63;
    int node0 = blockIdx.x * 64 + (threadIdx.x >> 6) * 16;
    if (node0 >= n) return;

    int arow = node0 + (lane & 15);
    if (arow >= n) arow = n - 1;
    const unsigned short* ap = hb + (size_t)arow * K + ((lane >> 4) << 3);

    f32x4 z = {0.f, 0.f, 0.f, 0.f};
    f32x4 accW[4] = {z, z, z, z};
    f32x4 accI[4] = {z, z, z, z};

#pragma unroll
    for (int kc = 0; kc < KC; ++kc) {
        bf16x8 a = *(const bf16x8*)(ap + kc * 32);
#pragma unroll
        for (int ct = 0; ct < 4; ++ct) {
            bf16x8 bw = *(const bf16x8*)(wf + ((((size_t)0 * KC + kc) * 4 + ct) * 64 + lane) * 8);
            bf16x8 bi = *(const bf16x8*)(wf + ((((size_t)1 * KC + kc) * 4 + ct) * 64 + lane) * 8);
            accW[ct] = __builtin_amdgcn_mfma_f32_16x16x32_bf16(a, bw, accW[ct], 0, 0, 0);
            accI[ct] = __builtin_amdgcn_mfma_f32_16x16x32_bf16(a, bi, accI[ct], 0, 0, 0);
        }
    }

    int colb = lane & 15;
    int rbase = node0 + ((lane >> 4) << 2);
    float sv[4];
#pragma unroll
    for (int j = 0; j < 4; ++j) {
        int r = rbase + j;
        sv[j] = (r < n) ? S[r] : 0.f;
    }
#pragma unroll
    for (int ct = 0; ct < 4; ++ct) {
        int c = ct * 16 + colb;
        float bb = bias[c];
#pragma unroll
        for (int j = 0; j < 4; ++j) {
            int r = rbase + j;
            if (r < n) {
                outb[(size_t)r * 64 + c] = f2bf(accW[ct][j] + bb);
                imb [(size_t)r * 64 + c] = f2bf(sv[j] * accI[ct][j]);
            }
        }
    }
}

// ---------------- Fused gather + GEMM (layers 2,3) ----------------
// Phase 1: 4 thr/node x 16ch gather conv result = imb[v] + sum outb[row];
//          leaky-relu; pack bf16 into padded LDS [64][LDSW].
// Phase 2: 4 waves x 16 nodes MFMA dual-GEMM from LDS -> outn, imbn.
__global__ __launch_bounds__(256) void fused_gg(const int* __restrict__ node_ptr,
        const int* __restrict__ rows, const unsigned short* __restrict__ outp,
        const unsigned short* __restrict__ imbp, const unsigned short* __restrict__ wf,
        const float* __restrict__ bias, const float* __restrict__ S,
        unsigned short* __restrict__ outn, unsigned short* __restrict__ imbn, int n) {
    __shared__ unsigned short hs[64 * LDSW];
    int t = threadIdx.x;
    int node0 = blockIdx.x * 64;
    int vl = t >> 2;
    int v = node0 + vl;
    int ch0 = (t & 3) * 16;
    int vv = (v < n) ? v : (n - 1);
    int p0 = node_ptr[vv], p1 = node_ptr[vv + 1];
    if (v >= n) p1 = p0;

    const unsigned short* ip = imbp + (size_t)vv * 64 + ch0;
    uint4 i0 = *(const uint4*)ip;
    uint4 i1 = *(const uint4*)(ip + 8);
    float acc[16] = { bflo(i0.x), bfhi(i0.x), bflo(i0.y), bfhi(i0.y),
                      bflo(i0.z), bfhi(i0.z), bflo(i0.w), bfhi(i0.w),
                      bflo(i1.x), bfhi(i1.x), bflo(i1.y), bfhi(i1.y),
                      bflo(i1.z), bfhi(i1.z), bflo(i1.w), bfhi(i1.w) };

    int i = p0;
    for (; i + 4 <= p1; i += 4) {
        int r0 = rows[i], r1 = rows[i + 1], r2 = rows[i + 2], r3 = rows[i + 3];
        const unsigned short* a0 = outp + (size_t)r0 * 64 + ch0;
        const unsigned short* a1 = outp + (size_t)r1 * 64 + ch0;
        const unsigned short* a2 = outp + (size_t)r2 * 64 + ch0;
        const unsigned short* a3 = outp + (size_t)r3 * 64 + ch0;
        uint4 u0 = *(const uint4*)a0, v0 = *(const uint4*)(a0 + 8);
        uint4 u1 = *(const uint4*)a1, v1 = *(const uint4*)(a1 + 8);
        uint4 u2 = *(const uint4*)a2, v2 = *(const uint4*)(a2 + 8);
        uint4 u3 = *(const uint4*)a3, v3 = *(const uint4*)(a3 + 8);
        acc[0]  += bflo(u0.x) + bflo(u1.x) + bflo(u2.x) + bflo(u3.x);
        acc[1]  += bfhi(u0.x) + bfhi(u1.x) + bfhi(u2.x) + bfhi(u3.x);
        acc[2]  += bflo(u0.y) + bflo(u1.y) + bflo(u2.y) + bflo(u3.y);
        acc[3]  += bfhi(u0.y) + bfhi(u1.y) + bfhi(u2.y) + bfhi(u3.y);
        acc[4]  += bflo(u0.z) + bflo(u1.z) + bflo(u2.z) + bflo(u3.z);
        acc[5]  += bfhi(u0.z) + bfhi(u1.z) + bfhi(u2.z) + bfhi(u3.z);
        acc[6]  += bflo(u0.w) + bflo(u1.w) + bflo(u2.w) + bflo(u3.w);
        acc[7]  += bfhi(u0.w) + bfhi(u1.w) + bfhi(u2.w) + bfhi(u3.w);
        acc[8]  += bflo(v0.x) + bflo(v1.x) + bflo(v2.x) + bflo(v3.x);
        acc[9]  += bfhi(v0.x) + bfhi(v1.x) + bfhi(v2.x) + bfhi(v3.x);
        acc[10] += bflo(v0.y) + bflo(v1.y) + bflo(v2.y) + bflo(v3.y);
        acc[11] += bfhi(v0.y) + bfhi(v1.y) + bfhi(v2.y) + bfhi(v3.y);
        acc[12] += bflo(v0.z) + bflo(v1.z) + bflo(v2.z) + bflo(v3.z);
        acc[13] += bfhi(v0.z) + bfhi(v1.z) + bfhi(v2.z) + bfhi(v3.z);
        acc[14] += bflo(v0.w) + bflo(v1.w) + bflo(v2.w) + bflo(v3.w);
        acc[15] += bfhi(v0.w) + bfhi(v1.w) + bfhi(v2.w) + bfhi(v3.w);
    }
    for (; i < p1; ++i) {
        int r = rows[i];
        const unsigned short* a = outp + (size_t)r * 64 + ch0;
        uint4 u = *(const uint4*)a, w = *(const uint4*)(a + 8);
        acc[0]  += bflo(u.x); acc[1]  += bfhi(u.x);
        acc[2]  += bflo(u.y); acc[3]  += bfhi(u.y);
        acc[4]  += bflo(u.z); acc[5]  += bfhi(u.z);
        acc[6]  += bflo(u.w); acc[7]  += bfhi(u.w);
        acc[8]  += bflo(w.x); acc[9]  += bfhi(w.x);
        acc[10] += bflo(w.y); acc[11] += bfhi(w.y);
        acc[12] += bflo(w.z); acc[13] += bfhi(w.z);
        acc[14] += bflo(w.w); acc[15] += bfhi(w.w);
    }
    // leaky-relu + bf16 pack into LDS
    unsigned pw[8];
#pragma unroll
    for (int q = 0; q < 8; ++q) {
        float e0 = acc[2 * q], e1 = acc[2 * q + 1];
        e0 = (e0 >= 0.f) ? e0 : 0.2f * e0;
        e1 = (e1 >= 0.f) ? e1 : 0.2f * e1;
        pw[q] = (unsigned)f2bf(e0) | ((unsigned)f2bf(e1) << 16);
    }
    *(uint4*)(&hs[vl * LDSW + ch0])     = make_uint4(pw[0], pw[1], pw[2], pw[3]);
    *(uint4*)(&hs[vl * LDSW + ch0 + 8]) = make_uint4(pw[4], pw[5], pw[6], pw[7]);
    __syncthreads();

    // ---- Phase 2: MFMA dual-GEMM (K=64) from LDS ----
    int lane = t & 63;
    int wnode0 = node0 + (t >> 6) * 16;
    int lrow = (t >> 6) * 16 + (lane & 15);
    int koff = (lane >> 4) << 3;

    f32x4 z = {0.f, 0.f, 0.f, 0.f};
    f32x4 accW[4] = {z, z, z, z};
    f32x4 accI[4] = {z, z, z, z};

#pragma unroll
    for (int kc = 0; kc < 2; ++kc) {
        bf16x8 a = *(const bf16x8*)(&hs[lrow * LDSW + kc * 32 + koff]);
#pragma unroll
        for (int ct = 0; ct < 4; ++ct) {
            bf16x8 bw = *(const bf16x8*)(wf + ((((size_t)0 * 2 + kc) * 4 + ct) * 64 + lane) * 8);
            bf16x8 bi = *(const bf16x8*)(wf + ((((size_t)1 * 2 + kc) * 4 + ct) * 64 + lane) * 8);
            accW[ct] = __builtin_amdgcn_mfma_f32_16x16x32_bf16(a, bw, accW[ct], 0, 0, 0);
            accI[ct] = __builtin_amdgcn_mfma_f32_16x16x32_bf16(a, bi, accI[ct], 0, 0, 0);
        }
    }

    int colb = lane & 15;
    int rbase = wnode0 + ((lane >> 4) << 2);
    float sv[4];
#pragma unroll
    for (int j = 0; j < 4; ++j) {
        int r = rbase + j;
        sv[j] = (r < n) ? S[r] : 0.f;
    }
#pragma unroll
    for (int ct = 0; ct < 4; ++ct) {
        int c = ct * 16 + colb;
        float bb = bias[c];
#pragma unroll
        for (int j = 0; j < 4; ++j) {
            int r = rbase + j;
            if (r < n) {
                outn[(size_t)r * 64 + c] = f2bf(accW[ct][j] + bb);
                imbn[(size_t)r * 64 + c] = f2bf(sv[j] * accI[ct][j]);
            }
        }
    }
}

// ---------------- Final gather + FC head fused ----------------
__global__ __launch_bounds__(256) void gather_fc(const int* __restrict__ node_ptr,
        const int* __restrict__ rows, const unsigned short* __restrict__ outp,
        const unsigned short* __restrict__ imbp, const float* __restrict__ Wfc,
        const float* __restrict__ bfc, float* __restrict__ o, int n) {
    int t = threadIdx.x;
    int v = blockIdx.x * 64 + (t >> 2);
    if (v >= n) return;
    int ch0 = (t & 3) * 16;
    int p0 = node_ptr[v], p1 = node_ptr[v + 1];

    const unsigned short* ip = imbp + (size_t)v * 64 + ch0;
    uint4 i0 = *(const uint4*)ip;
    uint4 i1 = *(const uint4*)(ip + 8);
    float acc[16] = { bflo(i0.x), bfhi(i0.x), bflo(i0.y), bfhi(i0.y),
                      bflo(i0.z), bfhi(i0.z), bflo(i0.w), bfhi(i0.w),
                      bflo(i1.x), bfhi(i1.x), bflo(i1.y), bfhi(i1.y),
                      bflo(i1.z), bfhi(i1.z), bflo(i1.w), bfhi(i1.w) };

    int i = p0;
    for (; i + 4 <= p1; i += 4) {
        int r0 = rows[i], r1 = rows[i + 1], r2 = rows[i + 2], r3 = rows[i + 3];
        const unsigned short* a0 = outp + (size_t)r0 * 64 + ch0;
        const unsigned short* a1 = outp + (size_t)r1 * 64 + ch0;
        const unsigned short* a2 = outp + (size_t)r2 * 64 + ch0;
        const unsigned short* a3 = outp + (size_t)r3 * 64 + ch0;
        uint4 u0 = *(const uint4*)a0, v0 = *(const uint4*)(a0 + 8);
        uint4 u1 = *(const uint4*)a1, v1 = *(const uint4*)(a1 + 8);
        uint4 u2 = *(const uint4*)a2, v2 = *(const uint4*)(a2 + 8);
        uint4 u3 = *(const uint4*)a3, v3 = *(const uint4*)(a3 + 8);
        acc[0]  += bflo(u0.x) + bflo(u1.x) + bflo(u2.x) + bflo(u3.x);
        acc[1]  += bfhi(u0.x) + bfhi(u1.x) + bfhi(u2.x) + bfhi(u3.x);
        acc[2]  += bflo(u0.y) + bflo(u1.y) + bflo(u2.y) + bflo(u3.y);
        acc[3]  += bfhi(u0.y) + bfhi(u1.y) + bfhi(u2.y) + bfhi(u3.y);
        acc[4]  += bflo(u0.z) + bflo(u1.z) + bflo(u2.z) + bflo(u3.z);
        acc[5]  += bfhi(u0.z) + bfhi(u1.z) + bfhi(u2.z) + bfhi(u3.z);
        acc[6]  += bflo(u0.w) + bflo(u1.w) + bflo(u2.w) + bflo(u3.w);
        acc[7]  += bfhi(u0.w) + bfhi(u1.w) + bfhi(u2.w) + bfhi(u3.w);
        acc[8]  += bflo(v0.x) + bflo(v1.x) + bflo(v2.x) + bflo(v3.x);
        acc[9]  += bfhi(v0.x) + bfhi(v1.x) + bfhi(v2.x) + bfhi(v3.x);
        acc[10] += bflo(v0.y) + bflo(v1.y) + bflo(v2.y) + bflo(v3.y);
        acc[11] += bfhi(v0.y) + bfhi(v1.y) + bfhi(v2.y) + bfhi(v3.y);
        acc[12] += bflo(v0.z) + bflo(v1.z) + bflo(v2.z) + bflo(v3.z);
        acc[13] += bfhi(v0.z) + bfhi(v1.z) + bfhi(v2.z) + bfhi(v3.z);
        acc[14] += bflo(v0.w) + bflo(v1.w) + bflo(v2.w) + bflo(v3.w);
        acc[15] += bfhi(v0.w) + bfhi(v1.w) + bfhi(v2.w) + bfhi(v3.w);
    }
    for (; i < p1; ++i) {
        int r = rows[i];
        const unsigned short* a = outp + (size_t)r * 64 + ch0;
        uint4 u = *(const uint4*)a, w = *(const uint4*)(a + 8);
        acc[0]  += bflo(u.x); acc[1]  += bfhi(u.x);
        acc[2]  += bflo(u.y); acc[3]  += bfhi(u.y);
        acc[4]  += bflo(u.z); acc[5]  += bfhi(u.z);
        acc[6]  += bflo(u.w); acc[7]  += bfhi(u.w);
        acc[8]  += bflo(w.x); acc[9]  += bfhi(w.x);
        acc[10] += bflo(w.y); acc[11] += bfhi(w.y);
        acc[12] += bflo(w.z); acc[13] += bfhi(w.z);
        acc[14] += bflo(w.w); acc[15] += bfhi(w.w);
    }
    // FC: partial dot over this thread's 16 channels, reduce across group of 4
    float dot = 0.f;
#pragma unroll
    for (int j = 0; j < 16; ++j) dot = fmaf(acc[j], Wfc[ch0 + j], dot);
    dot += __shfl_down(dot, 2, 4);
    dot += __shfl_down(dot, 1, 4);
    if ((t & 3) == 0) o[v] = dot + bfc[0];
}

extern "C" void kernel_launch(void* const* d_in, const int* in_sizes, int n_in,
                              void* d_out, int out_size, void* d_ws, size_t ws_size,
                              hipStream_t stream) {
    const float* x   = (const float*)d_in[0];
    const int*   ei  = (const int*)d_in[1];
    const float* imp = (const float*)d_in[2];
    const float* W1  = (const float*)d_in[3];
    const float* b1  = (const float*)d_in[4];
    const float* Wi1 = (const float*)d_in[5];
    const float* W2  = (const float*)d_in[6];
    const float* b2  = (const float*)d_in[7];
    const float* Wi2 = (const float*)d_in[8];
    const float* W3  = (const float*)d_in[9];
    const float* b3  = (const float*)d_in[10];
    const float* Wi3 = (const float*)d_in[11];
    const float* Wfc = (const float*)d_in[12];
    const float* bfc = (const float*)d_in[13];

    int n = in_sizes[0] / 32;      // 100000
    int E = in_sizes[1] / 2;       // 1600000
    const int* row = ei;
    const int* col = ei + E;
    int nbin = (n + BINW - 1) / BINW;   // 782

    // ---- workspace: bump allocator, 64B-aligned regions ----
    size_t off = 0;
    auto alloc = [&](size_t words) {
        size_t cur = off;
        off += (words + 15) & ~(size_t)15;
        return cur;
    };
    int* wsw = (int*)d_ws;
    float*          S        = (float*)(wsw + alloc(n));
    int*            node_ptr = wsw + alloc((size_t)n + 1);
    int*            binCnt   = wsw + alloc(1024);
    int*            binBase  = wsw + alloc(1024);
    int*            cursor   = wsw + alloc(1024);
    int*            binBuf   = wsw + alloc(E);
    int*            rowsA    = wsw + alloc(E);
    unsigned short* outbA    = (unsigned short*)(wsw + alloc((size_t)n * 32));
    unsigned short* imbA     = (unsigned short*)(wsw + alloc((size_t)n * 32));
    unsigned short* outbB    = (unsigned short*)(wsw + alloc((size_t)n * 32));
    unsigned short* imbB     = (unsigned short*)(wsw + alloc((size_t)n * 32));
    unsigned short* xb       = (unsigned short*)(wsw + alloc((size_t)n * 16));
    unsigned short* wf1      = (unsigned short*)(wsw + alloc(2048));
    unsigned short* wf2      = (unsigned short*)(wsw + alloc(4096));
    unsigned short* wf3      = (unsigned short*)(wsw + alloc(4096));

    int gA = (E + CHUNK - 1) / CHUNK;

    hipMemsetAsync(binCnt, 0, 1024 * sizeof(int), stream);
    bin_count  <<<gA, 256, 0, stream>>>(col, binCnt, E, nbin);
    bin_prefix <<<1, 1024, 0, stream>>>(binCnt, binBase, cursor, node_ptr, nbin, n, E);
    bin_scatter<<<gA, 256, 0, stream>>>(row, col, binBase, cursor, binBuf, E, nbin);
    bin_phaseB <<<nbin, 256, 0, stream>>>(binCnt, binBase, binBuf, imp, rowsA, node_ptr, S, n);

    long total8 = (long)n * 32 / 8;
    xconv<<<(int)((total8 + 255) / 256), 256, 0, stream>>>(x, xb, total8);
    wpack_all<<<3, 256, 0, stream>>>(W1, Wi1, W2, Wi2, W3, Wi3, wf1, wf2, wf3);

    int gm = (n + 63) / 64;     // 64 nodes per block everywhere

    // Layer 1: dense GEMM on x
    gemm_mfma<32><<<gm, 256, 0, stream>>>(xb, wf1, b1, S, outbA, imbA, n);
    // Layer 2: gather(conv1) + relu + GEMM(W2,Wi2)
    fused_gg<<<gm, 256, 0, stream>>>(node_ptr, rowsA, outbA, imbA, wf2, b2, S, outbB, imbB, n);
    // Layer 3: gather(conv2) + relu + GEMM(W3,Wi3)
    fused_gg<<<gm, 256, 0, stream>>>(node_ptr, rowsA, outbB, imbB, wf3, b3, S, outbA, imbA, n);
    // Final: gather(conv3) + FC head
    gather_fc<<<gm, 256, 0, stream>>>(node_ptr, rowsA, outbA, imbA, Wfc, bfc, (float*)d_out, n);
}

// Round 11
// 254.749 us; speedup vs baseline: 1.2465x; 1.0773x over previous
//
#include <hip/hip_runtime.h>

// ImpedanceAwareGCN on MI355X.
// segment_sum(out[row] + imp[row]*imp_mod[col], col)
//   = scatter_add(out) + S[v]*imp_mod[v],  S[v] = sum_{e: col=v} imp[row[e]].
// R11: de-fuse R10's gather+GEMM (fusion cut occupancy 66->26% and cost 8us/layer;
// gather is latency-bound and needs waves). Keep bf16 imb + gather_fc fusion.
// Build: single-pass binning into fixed-capacity segments (kills bin_count pass).

#define BINW    128          // nodes per bin (bin = col >> 7)
#define CHUNK   4096         // edges per binning block
#define BINFIX  3072         // fixed per-bin segment capacity (mean 2046, +22 sigma)

typedef __attribute__((ext_vector_type(8))) short bf16x8;
typedef __attribute__((ext_vector_type(4))) float f32x4;

__device__ inline unsigned short f2bf(float f) {   // RNE fp32->bf16
    unsigned u = __float_as_uint(f);
    unsigned r = u + 0x7fffu + ((u >> 16) & 1u);
    return (unsigned short)(r >> 16);
}
__device__ inline float bflo(unsigned u) { return __uint_as_float(u << 16); }
__device__ inline float bfhi(unsigned u) { return __uint_as_float(u & 0xffff0000u); }

// ---------------- Single-pass binning into fixed-capacity segments ----------------
// binBuf[b*BINFIX + cursor[b]++] = (row<<7)|(col&127). Segment bases are FIXED
// (b*BINFIX), so per-block span reservation needs no global prefix (R5 bug N/A).
__global__ __launch_bounds__(256) void bin_scatter_fix(const int* __restrict__ row,
        const int* __restrict__ col, int* __restrict__ cursor,
        int* __restrict__ binBuf, int E, int nbin) {
    __shared__ int      wpackl[CHUNK];
    __shared__ unsigned short wbin[CHUNK];
    __shared__ int      hist[1024];
    __shared__ int      basel[1024];

    int e0 = blockIdx.x * CHUNK;
    int cnt = E - e0; if (cnt > CHUNK) cnt = CHUNK;
    if (cnt <= 0) return;
    int tid = threadIdx.x;

    for (int b = tid; b < nbin; b += 256) hist[b] = 0;
    for (int i = tid; i < cnt; i += 256) {
        int r = row[e0 + i], v = col[e0 + i];
        wpackl[i] = (r << 7) | (v & (BINW - 1));
        wbin[i]  = (unsigned short)(v >> 7);
    }
    __syncthreads();
    for (int i = tid; i < cnt; i += 256) atomicAdd(&hist[wbin[i]], 1);
    __syncthreads();
    for (int b = tid; b < nbin; b += 256) {
        int h = hist[b];
        basel[b] = h ? atomicAdd(&cursor[b], h) : 0;   // offset within bin segment
        hist[b] = 0;
    }
    __syncthreads();
    for (int i = tid; i < cnt; i += 256) {
        int b = wbin[i];
        int off = basel[b] + atomicAdd(&hist[b], 1);
        if (off < BINFIX)                               // ~1e-100 overflow guard
            binBuf[(size_t)b * BINFIX + off] = wpackl[i];
    }
}

// ---------------- Prefix: compact CSR bases from cursor counts ----------------
__global__ __launch_bounds__(1024) void bin_prefix(const int* __restrict__ cursor,
        int* __restrict__ binBase, int* __restrict__ node_ptr, int nbin, int n) {
    __shared__ int sa[1024];
    int tid = threadIdx.x;
    int c = (tid < nbin) ? cursor[tid] : 0;
    if (c > BINFIX) c = BINFIX;
    sa[tid] = c;
    __syncthreads();
    for (int d = 1; d < 1024; d <<= 1) {
        int v = sa[tid] + ((tid >= d) ? sa[tid - d] : 0);
        __syncthreads();
        sa[tid] = v;
        __syncthreads();
    }
    if (tid < nbin) binBase[tid] = sa[tid] - c;        // exclusive
    if (tid == 0) node_ptr[n] = sa[1023];              // total rows written
}

// ---------------- Phase B: counting-sort each bin in LDS -> CSR rows, node_ptr, S ----------------
__global__ __launch_bounds__(256) void bin_phaseB(const int* __restrict__ cursor,
        const int* __restrict__ binBase, const int* __restrict__ binBuf,
        const float* __restrict__ imp, int* __restrict__ rows,
        int* __restrict__ node_ptr, float* __restrict__ S, int n) {
    __shared__ int ein[BINFIX];
    __shared__ int sorted[BINFIX];
    __shared__ int dhist[BINW];
    __shared__ int dpre[BINW];
    __shared__ int doff[BINW];

    int b = blockIdx.x;
    int srcb = b * BINFIX;
    int dstb = binBase[b];
    int cnt = cursor[b]; if (cnt > BINFIX) cnt = BINFIX;
    int tid = threadIdx.x;
    int v0 = b << 7;

    if (tid < BINW) { dhist[tid] = 0; doff[tid] = 0; }
    for (int i = tid; i < cnt; i += 256) ein[i] = binBuf[srcb + i];
    __syncthreads();
    for (int i = tid; i < cnt; i += 256) atomicAdd(&dhist[ein[i] & (BINW - 1)], 1);
    __syncthreads();
    if (tid < BINW) dpre[tid] = dhist[tid];
    __syncthreads();
    for (int d = 1; d < BINW; d <<= 1) {
        int v = 0;
        if (tid < BINW) v = dpre[tid] + ((tid >= d) ? dpre[tid - d] : 0);
        __syncthreads();
        if (tid < BINW) dpre[tid] = v;
        __syncthreads();
    }
    if (tid < BINW) {
        int v = v0 + tid;
        if (v < n) node_ptr[v] = dstb + dpre[tid] - dhist[tid];
    }
    __syncthreads();
    for (int i = tid; i < cnt; i += 256) {
        int w = ein[i];
        int j = w & (BINW - 1);
        int off = atomicAdd(&doff[j], 1);
        sorted[dpre[j] - dhist[j] + off] = w >> 7;
    }
    __syncthreads();
    for (int i = tid; i < cnt; i += 256) rows[dstb + i] = sorted[i];
    // S[v] = sum imp[row] over node's edges (imp L2-resident, 400KB)
    if (tid < BINW) {
        int v = v0 + tid;
        if (v < n) {
            int a = dpre[tid] - dhist[tid], e = dpre[tid];
            float s0 = 0.f, s1 = 0.f;
            int i = a;
            for (; i + 2 <= e; i += 2) { s0 += imp[sorted[i]]; s1 += imp[sorted[i + 1]]; }
            if (i < e) s0 += imp[sorted[i]];
            S[v] = s0 + s1;
        }
    }
}

// ---------------- x -> bf16 convert ----------------
__global__ __launch_bounds__(256) void xconv(const float* __restrict__ x,
        unsigned short* __restrict__ xb, long total8) {
    long i = (long)blockIdx.x * 256 + threadIdx.x;
    if (i >= total8) return;
    const float4* xp = (const float4*)(x + i * 8);
    float4 a = xp[0], b = xp[1];
    uint4 w = make_uint4(
        (unsigned)f2bf(a.x) | ((unsigned)f2bf(a.y) << 16),
        (unsigned)f2bf(a.z) | ((unsigned)f2bf(a.w) << 16),
        (unsigned)f2bf(b.x) | ((unsigned)f2bf(b.y) << 16),
        (unsigned)f2bf(b.z) | ((unsigned)f2bf(b.w) << 16));
    *(uint4*)(xb + i * 8) = w;
}

// ---------------- weight pack: fragment layout [m][kc][ct][lane][8], bf16 ----------------
__global__ __launch_bounds__(256) void wpack_all(
        const float* __restrict__ W1, const float* __restrict__ Wi1,
        const float* __restrict__ W2, const float* __restrict__ Wi2,
        const float* __restrict__ W3, const float* __restrict__ Wi3,
        unsigned short* __restrict__ wf1, unsigned short* __restrict__ wf2,
        unsigned short* __restrict__ wf3) {
    int blk = blockIdx.x;
    const float *W, *Wi; unsigned short* dst; int KC;
    if (blk == 0)      { W = W1; Wi = Wi1; dst = wf1; KC = 1; }
    else if (blk == 1) { W = W2; Wi = Wi2; dst = wf2; KC = 2; }
    else               { W = W3; Wi = Wi3; dst = wf3; KC = 2; }
    int SLOTS = 2 * KC * 4 * 64;
    for (int s = threadIdx.x; s < SLOTS; s += 256) {
        int l  = s & 63;
        int ct = (s >> 6) & 3;
        int kc = (s >> 8) % KC;
        int m  = s / (256 * KC);
        int k   = kc * 32 + ((l >> 4) << 3);
        int c   = ct * 16 + (l & 15);
        const float* src = m ? Wi : W;
        unsigned short t[8];
#pragma unroll
        for (int e = 0; e < 8; ++e) t[e] = f2bf(src[(k + e) * 64 + c]);
        *(uint4*)(dst + (size_t)s * 8) = make_uint4(
            (unsigned)t[0] | ((unsigned)t[1] << 16),
            (unsigned)t[2] | ((unsigned)t[3] << 16),
            (unsigned)t[4] | ((unsigned)t[5] << 16),
            (unsigned)t[6] | ((unsigned)t[7] << 16));
    }
}

// ---------------- MFMA dual GEMM: outb = bf16(in@W+b), imb = bf16(S*(in@Wi)) ----------------
template<int K>
__global__ __launch_bounds__(256) void gemm_mfma(
        const unsigned short* __restrict__ hb, const unsigned short* __restrict__ wf,
        const float* __restrict__ bias, const float* __restrict__ S,
        unsigned short* __restrict__ outb, unsigned short* __restrict__ imb, int n) {
    constexpr int KC = K / 32;
    int lane = threadIdx.x & 63;
    int node0 = blockIdx.x * 64 + (threadIdx.x >> 6) * 16;
    if (node0 >= n) return;

    int arow = node0 + (lane & 15);
    if (arow >= n) arow = n - 1;
    const unsigned short* ap = hb + (size_t)arow * K + ((lane >> 4) << 3);

    f32x4 z = {0.f, 0.f, 0.f, 0.f};
    f32x4 accW[4] = {z, z, z, z};
    f32x4 accI[4] = {z, z, z, z};

#pragma unroll
    for (int kc = 0; kc < KC; ++kc) {
        bf16x8 a = *(const bf16x8*)(ap + kc * 32);
#pragma unroll
        for (int ct = 0; ct < 4; ++ct) {
            bf16x8 bw = *(const bf16x8*)(wf + ((((size_t)0 * KC + kc) * 4 + ct) * 64 + lane) * 8);
            bf16x8 bi = *(const bf16x8*)(wf + ((((size_t)1 * KC + kc) * 4 + ct) * 64 + lane) * 8);
            accW[ct] = __builtin_amdgcn_mfma_f32_16x16x32_bf16(a, bw, accW[ct], 0, 0, 0);
            accI[ct] = __builtin_amdgcn_mfma_f32_16x16x32_bf16(a, bi, accI[ct], 0, 0, 0);
        }
    }

    int colb = lane & 15;
    int rbase = node0 + ((lane >> 4) << 2);
    float sv[4];
#pragma unroll
    for (int j = 0; j < 4; ++j) {
        int r = rbase + j;
        sv[j] = (r < n) ? S[r] : 0.f;
    }
#pragma unroll
    for (int ct = 0; ct < 4; ++ct) {
        int c = ct * 16 + colb;
        float bb = bias[c];
#pragma unroll
        for (int j = 0; j < 4; ++j) {
            int r = rbase + j;
            if (r < n) {
                outb[(size_t)r * 64 + c] = f2bf(accW[ct][j] + bb);
                imb [(size_t)r * 64 + c] = f2bf(sv[j] * accI[ct][j]);
            }
        }
    }
}

// ---------------- Gather (CSR): 8 thr/node, acc init from bf16 imb, relu -> bf16 hb ----------------
__global__ __launch_bounds__(256) void gather_hb(const int* __restrict__ node_ptr,
        const int* __restrict__ rows, const unsigned short* __restrict__ outb,
        const unsigned short* __restrict__ imb, unsigned short* __restrict__ hb, int n) {
    int t = threadIdx.x;
    int v = blockIdx.x * 32 + (t >> 3);
    if (v >= n) return;
    int sub = t & 7;                       // channels [8*sub, 8*sub+8)
    int p0 = node_ptr[v], p1 = node_ptr[v + 1];

    const unsigned short* ip = imb + (size_t)v * 64 + sub * 8;
    uint4 i0 = *(const uint4*)ip;
    float acc[8] = { bflo(i0.x), bfhi(i0.x), bflo(i0.y), bfhi(i0.y),
                     bflo(i0.z), bfhi(i0.z), bflo(i0.w), bfhi(i0.w) };

    int i = p0;
    for (; i + 4 <= p1; i += 4) {
        int r0 = rows[i], r1 = rows[i + 1], r2 = rows[i + 2], r3 = rows[i + 3];
        uint4 a0 = *(const uint4*)(outb + (size_t)r0 * 64 + sub * 8);
        uint4 a1 = *(const uint4*)(outb + (size_t)r1 * 64 + sub * 8);
        uint4 a2 = *(const uint4*)(outb + (size_t)r2 * 64 + sub * 8);
        uint4 a3 = *(const uint4*)(outb + (size_t)r3 * 64 + sub * 8);
        acc[0] += bflo(a0.x) + bflo(a1.x) + bflo(a2.x) + bflo(a3.x);
        acc[1] += bfhi(a0.x) + bfhi(a1.x) + bfhi(a2.x) + bfhi(a3.x);
        acc[2] += bflo(a0.y) + bflo(a1.y) + bflo(a2.y) + bflo(a3.y);
        acc[3] += bfhi(a0.y) + bfhi(a1.y) + bfhi(a2.y) + bfhi(a3.y);
        acc[4] += bflo(a0.z) + bflo(a1.z) + bflo(a2.z) + bflo(a3.z);
        acc[5] += bfhi(a0.z) + bfhi(a1.z) + bfhi(a2.z) + bfhi(a3.z);
        acc[6] += bflo(a0.w) + bflo(a1.w) + bflo(a2.w) + bflo(a3.w);
        acc[7] += bfhi(a0.w) + bfhi(a1.w) + bfhi(a2.w) + bfhi(a3.w);
    }
    for (; i < p1; ++i) {
        int r = rows[i];
        uint4 a = *(const uint4*)(outb + (size_t)r * 64 + sub * 8);
        acc[0] += bflo(a.x); acc[1] += bfhi(a.x);
        acc[2] += bflo(a.y); acc[3] += bfhi(a.y);
        acc[4] += bflo(a.z); acc[5] += bfhi(a.z);
        acc[6] += bflo(a.w); acc[7] += bfhi(a.w);
    }
    unsigned w[4];
#pragma unroll
    for (int q = 0; q < 4; ++q) {
        float v0 = acc[2 * q], v1 = acc[2 * q + 1];
        v0 = (v0 >= 0.f) ? v0 : 0.2f * v0;
        v1 = (v1 >= 0.f) ? v1 : 0.2f * v1;
        w[q] = (unsigned)f2bf(v0) | ((unsigned)f2bf(v1) << 16);
    }
    *(uint4*)(hb + (size_t)v * 64 + sub * 8) = make_uint4(w[0], w[1], w[2], w[3]);
}

// ---------------- Final gather + FC head fused (no MFMA -> low VGPR, high occ) ----------------
__global__ __launch_bounds__(256) void gather_fc(const int* __restrict__ node_ptr,
        const int* __restrict__ rows, const unsigned short* __restrict__ outb,
        const unsigned short* __restrict__ imb, const float* __restrict__ Wfc,
        const float* __restrict__ bfc, float* __restrict__ o, int n) {
    int t = threadIdx.x;
    int v = blockIdx.x * 32 + (t >> 3);
    if (v >= n) return;
    int sub = t & 7;
    int p0 = node_ptr[v], p1 = node_ptr[v + 1];

    const unsigned short* ip = imb + (size_t)v * 64 + sub * 8;
    uint4 i0 = *(const uint4*)ip;
    float acc[8] = { bflo(i0.x), bfhi(i0.x), bflo(i0.y), bfhi(i0.y),
                     bflo(i0.z), bfhi(i0.z), bflo(i0.w), bfhi(i0.w) };

    int i = p0;
    for (; i + 4 <= p1; i += 4) {
        int r0 = rows[i], r1 = rows[i + 1], r2 = rows[i + 2], r3 = rows[i + 3];
        uint4 a0 = *(const uint4*)(outb + (size_t)r0 * 64 + sub * 8);
        uint4 a1 = *(const uint4*)(outb + (size_t)r1 * 64 + sub * 8);
        uint4 a2 = *(const uint4*)(outb + (size_t)r2 * 64 + sub * 8);
        uint4 a3 = *(const uint4*)(outb + (size_t)r3 * 64 + sub * 8);
        acc[0] += bflo(a0.x) + bflo(a1.x) + bflo(a2.x) + bflo(a3.x);
        acc[1] += bfhi(a0.x) + bfhi(a1.x) + bfhi(a2.x) + bfhi(a3.x);
        acc[2] += bflo(a0.y) + bflo(a1.y) + bflo(a2.y) + bflo(a3.y);
        acc[3] += bfhi(a0.y) + bfhi(a1.y) + bfhi(a2.y) + bfhi(a3.y);
        acc[4] += bflo(a0.z) + bflo(a1.z) + bflo(a2.z) + bflo(a3.z);
        acc[5] += bfhi(a0.z) + bfhi(a1.z) + bfhi(a2.z) + bfhi(a3.z);
        acc[6] += bflo(a0.w) + bflo(a1.w) + bflo(a2.w) + bflo(a3.w);
        acc[7] += bfhi(a0.w) + bfhi(a1.w) + bfhi(a2.w) + bfhi(a3.w);
    }
    for (; i < p1; ++i) {
        int r = rows[i];
        uint4 a = *(const uint4*)(outb + (size_t)r * 64 + sub * 8);
        acc[0] += bflo(a.x); acc[1] += bfhi(a.x);
        acc[2] += bflo(a.y); acc[3] += bfhi(a.y);
        acc[4] += bflo(a.z); acc[5] += bfhi(a.z);
        acc[6] += bflo(a.w); acc[7] += bfhi(a.w);
    }
    float dot = 0.f;
#pragma unroll
    for (int j = 0; j < 8; ++j) dot = fmaf(acc[j], Wfc[sub * 8 + j], dot);
    dot += __shfl_down(dot, 4, 8);
    dot += __shfl_down(dot, 2, 8);
    dot += __shfl_down(dot, 1, 8);
    if (sub == 0) o[v] = dot + bfc[0];
}

extern "C" void kernel_launch(void* const* d_in, const int* in_sizes, int n_in,
                              void* d_out, int out_size, void* d_ws, size_t ws_size,
                              hipStream_t stream) {
    const float* x   = (const float*)d_in[0];
    const int*   ei  = (const int*)d_in[1];
    const float* imp = (const float*)d_in[2];
    const float* W1  = (const float*)d_in[3];
    const float* b1  = (const float*)d_in[4];
    const float* Wi1 = (const float*)d_in[5];
    const float* W2  = (const float*)d_in[6];
    const float* b2  = (const float*)d_in[7];
    const float* Wi2 = (const float*)d_in[8];
    const float* W3  = (const float*)d_in[9];
    const float* b3  = (const float*)d_in[10];
    const float* Wi3 = (const float*)d_in[11];
    const float* Wfc = (const float*)d_in[12];
    const float* bfc = (const float*)d_in[13];

    int n = in_sizes[0] / 32;      // 100000
    int E = in_sizes[1] / 2;       // 1600000
    const int* row = ei;
    const int* col = ei + E;
    int nbin = (n + BINW - 1) / BINW;   // 782

    // ---- workspace: bump allocator, 64B-aligned regions (~62 MB) ----
    size_t off = 0;
    auto alloc = [&](size_t words) {
        size_t cur = off;
        off += (words + 15) & ~(size_t)15;
        return cur;
    };
    int* wsw = (int*)d_ws;
    float*          S        = (float*)(wsw + alloc(n));
    int*            node_ptr = wsw + alloc((size_t)n + 1);
    int*            cursor   = wsw + alloc(1024);
    int*            binBase  = wsw + alloc(1024);
    int*            binBuf   = wsw + alloc((size_t)nbin * BINFIX);
    int*            rowsA    = wsw + alloc(E);
    unsigned short* outb     = (unsigned short*)(wsw + alloc((size_t)n * 32));
    unsigned short* imb      = (unsigned short*)(wsw + alloc((size_t)n * 32));
    unsigned short* hb       = (unsigned short*)(wsw + alloc((size_t)n * 32));
    unsigned short* xb       = (unsigned short*)(wsw + alloc((size_t)n * 16));
    unsigned short* wf1      = (unsigned short*)(wsw + alloc(2048));
    unsigned short* wf2      = (unsigned short*)(wsw + alloc(4096));
    unsigned short* wf3      = (unsigned short*)(wsw + alloc(4096));

    int gA = (E + CHUNK - 1) / CHUNK;

    hipMemsetAsync(cursor, 0, 1024 * sizeof(int), stream);
    bin_scatter_fix<<<gA, 256, 0, stream>>>(row, col, cursor, binBuf, E, nbin);
    bin_prefix     <<<1, 1024, 0, stream>>>(cursor, binBase, node_ptr, nbin, n);
    bin_phaseB     <<<nbin, 256, 0, stream>>>(cursor, binBase, binBuf, imp, rowsA, node_ptr, S, n);

    long total8 = (long)n * 32 / 8;
    xconv<<<(int)((total8 + 255) / 256), 256, 0, stream>>>(x, xb, total8);
    wpack_all<<<3, 256, 0, stream>>>(W1, Wi1, W2, Wi2, W3, Wi3, wf1, wf2, wf3);

    int gm = (n + 63) / 64;     // gemm blocks
    int gg = (n + 31) / 32;     // gather blocks

    // Layer 1: dense GEMM on x
    gemm_mfma<32><<<gm, 256, 0, stream>>>(xb, wf1, b1, S, outb, imb, n);
    gather_hb<<<gg, 256, 0, stream>>>(node_ptr, rowsA, outb, imb, hb, n);

    // Layer 2
    gemm_mfma<64><<<gm, 256, 0, stream>>>(hb, wf2, b2, S, outb, imb, n);
    gather_hb<<<gg, 256, 0, stream>>>(node_ptr, rowsA, outb, imb, hb, n);

    // Layer 3
    gemm_mfma<64><<<gm, 256, 0, stream>>>(hb, wf3, b3, S, outb, imb, n);
    gather_fc<<<gg, 256, 0, stream>>>(node_ptr, rowsA, outb, imb, Wfc, bfc, (float*)d_out, n);
}